// Round 4
// baseline (265.334 us; speedup 1.0000x reference)
//
#include <hip/hip_runtime.h>

// LSTM decoder: B=1024, H=16, 4H=64 gates, T=128 steps x 16 cells = 2048
// strictly-serial cell evaluations per batch chain. 1 chain = 1 wave =
// 1 SIMD (occupancy structurally pinned; all hiding is intra-wave ILP).
//
// Round-19 = round-18 (203.1us = ~238 cyc/cell: 184 busy / 54 exposed)
// with per-step amortized-overhead cuts (bit-identical numerics):
//  1. Step-loop unrolled x4 over a SLIDING 19-SLOT WINDOW: sub-step k
//     reads xw[k..k+15] (static idx), pred lands at xw[15+k]; ONE
//     shift-by-4 (15 movs) per 4 steps instead of 15 movs/step.
//     ~11 movs/step removed (~1.4 cyc/cell) + loop overhead /4.
//  2. pm = pend*wlk hoisted before cell 0 (pend final since prev step):
//     row_sum loses its head s_nop and the mul leaves the pred chain.
//
// Rejected-by-analysis this round: 2-chain/wave packing (MAC issue is the
// bottleneck; wall_pair ~290 > 238 -> slower); 2-accum MAC (same-accum
// spacing 4 cyc risks DPP-write hazard stall on every fmac); bf16 MFMA
// gate matmul (fragment shuffle cost >= DPP MAC cost + accuracy).
//
// Carried: per-lane one-gate mapping relabeled by probed permlane slots;
// 15 v_mul/v_fmac_f32_dpp fused gather-MACs (asm); 3 permlane16/32_swap
// gate exchange (depth-2); c in exp2-scaled domain; tanh tail
// fmaf(-ov,ec,ov)*rcp; DPP row-sum pred; lazy pred; pre-transformed window.

#define B_ 1024
#define A_ 16
#define T_ 128
#define R_ 128
#define H_ 16

typedef unsigned int u32x2 __attribute__((ext_vector_type(2)));

// Broadcast the 4 gate rows to all lanes (slot order probed at init).
__device__ __forceinline__ void gate_xchg(float act, int kp,
                                          float& s0, float& s1,
                                          float& s2, float& s3) {
#if __has_builtin(__builtin_amdgcn_permlane32_swap) && __has_builtin(__builtin_amdgcn_permlane16_swap)
    const unsigned a = __float_as_uint(act);
    const u32x2 pq = __builtin_amdgcn_permlane32_swap(a, a, false, false);
    const u32x2 rs = __builtin_amdgcn_permlane16_swap(pq.x, pq.x, false, false);
    const u32x2 tu = __builtin_amdgcn_permlane16_swap(pq.y, pq.y, false, false);
    s0 = __uint_as_float(rs.x); s1 = __uint_as_float(rs.y);
    s2 = __uint_as_float(tu.x); s3 = __uint_as_float(tu.y);
#else
    s0 = __shfl(act, kp,      64);
    s1 = __shfl(act, kp + 16, 64);
    s2 = __shfl(act, kp + 32, 64);
    s3 = __shfl(act, kp + 48, 64);
#endif
}

// Row-wide sum via DPP rotations, WITH head hazard nop (used where the
// input mul immediately precedes the asm).
__device__ __forceinline__ float row_sum(float m) {
    float pm = m;
    asm("s_nop 1\n\t"
        "v_add_f32_dpp %0, %0, %0 row_ror:8 row_mask:0xf bank_mask:0xf\n\t"
        "s_nop 1\n\t"
        "v_add_f32_dpp %0, %0, %0 row_ror:4 row_mask:0xf bank_mask:0xf\n\t"
        "s_nop 1\n\t"
        "v_add_f32_dpp %0, %0, %0 row_ror:2 row_mask:0xf bank_mask:0xf\n\t"
        "s_nop 1\n\t"
        "v_add_f32_dpp %0, %0, %0 row_ror:1 row_mask:0xf bank_mask:0xf"
        : "+v"(pm));
    return pm;
}

// Headless variant: caller guarantees >=2 VALU cycles between the write of
// pm and this asm (pm is computed BEFORE the preceding CELL, ~28 instrs).
__device__ __forceinline__ float row_sum_nohead(float pm) {
    asm("v_add_f32_dpp %0, %0, %0 row_ror:8 row_mask:0xf bank_mask:0xf\n\t"
        "s_nop 1\n\t"
        "v_add_f32_dpp %0, %0, %0 row_ror:4 row_mask:0xf bank_mask:0xf\n\t"
        "s_nop 1\n\t"
        "v_add_f32_dpp %0, %0, %0 row_ror:2 row_mask:0xf bank_mask:0xf\n\t"
        "s_nop 1\n\t"
        "v_add_f32_dpp %0, %0, %0 row_ror:1 row_mask:0xf bank_mask:0xf"
        : "+v"(pm));
    return pm;
}

// One LSTM cell; xz = fmaf(x, wij, bj) precomputed (pre-transformed window).
// Hazard note: fmaf(hk, w16[0], z0) reads hk and writes asm input z0, so it
// cannot be scheduled out from between hk's def and the asm block -> >=2
// cycles between the v_mul that writes hk and the first DPP read of hk.
#define CELL(xz)                                                              \
    do {                                                                      \
        float z0 = fmaf(hk, w16[0], (xz));                                    \
        float z1, z2, z3;                                                     \
        asm("v_mul_f32_dpp  %1, %4, %6  row_ror:1  row_mask:0xf bank_mask:0xf\n\t" \
            "v_mul_f32_dpp  %2, %4, %7  row_ror:2  row_mask:0xf bank_mask:0xf\n\t" \
            "v_mul_f32_dpp  %3, %4, %8  row_ror:3  row_mask:0xf bank_mask:0xf\n\t" \
            "v_fmac_f32_dpp %0, %4, %9  row_ror:4  row_mask:0xf bank_mask:0xf\n\t" \
            "v_fmac_f32_dpp %1, %4, %10 row_ror:5  row_mask:0xf bank_mask:0xf\n\t" \
            "v_fmac_f32_dpp %2, %4, %11 row_ror:6  row_mask:0xf bank_mask:0xf\n\t" \
            "v_fmac_f32_dpp %3, %4, %12 row_ror:7  row_mask:0xf bank_mask:0xf\n\t" \
            "v_fmac_f32_dpp %0, %4, %13 row_ror:8  row_mask:0xf bank_mask:0xf\n\t" \
            "v_fmac_f32_dpp %1, %4, %14 row_ror:9  row_mask:0xf bank_mask:0xf\n\t" \
            "v_fmac_f32_dpp %2, %4, %15 row_ror:10 row_mask:0xf bank_mask:0xf\n\t" \
            "v_fmac_f32_dpp %3, %4, %16 row_ror:11 row_mask:0xf bank_mask:0xf\n\t" \
            "v_fmac_f32_dpp %0, %4, %17 row_ror:12 row_mask:0xf bank_mask:0xf\n\t" \
            "v_fmac_f32_dpp %1, %4, %18 row_ror:13 row_mask:0xf bank_mask:0xf\n\t" \
            "v_fmac_f32_dpp %2, %4, %19 row_ror:14 row_mask:0xf bank_mask:0xf\n\t" \
            "v_fmac_f32_dpp %3, %4, %20 row_ror:15 row_mask:0xf bank_mask:0xf"     \
            : "+v"(z0), "=&v"(z1), "=&v"(z2), "=&v"(z3)                       \
            : "v"(hk),                                                        \
              "v"(w16[0]),  "v"(w16[1]),  "v"(w16[2]),  "v"(w16[3]),          \
              "v"(w16[4]),  "v"(w16[5]),  "v"(w16[6]),  "v"(w16[7]),          \
              "v"(w16[8]),  "v"(w16[9]),  "v"(w16[10]), "v"(w16[11]),         \
              "v"(w16[12]), "v"(w16[13]), "v"(w16[14]), "v"(w16[15]));        \
        const float z = (z0 + z1) + (z2 + z3);                                \
        const float e   = __builtin_amdgcn_exp2f(z);                          \
        const float sg  = __builtin_amdgcn_rcpf(1.0f + e);                    \
        const float act = fmaf(aAct, sg, bAct);                               \
        float iv, fv, gg, ov;                                                 \
        gate_xchg(act, kp, iv, fv, gg, ov);                                   \
        c = fmaf(fv, c, iv * gg);                                             \
        const float ec = __builtin_amdgcn_exp2f(c);                           \
        const float rc = __builtin_amdgcn_rcpf(1.0f + ec);                    \
        const float nm = fmaf(-ov, ec, ov);                                   \
        hk = nm * rc;                                                         \
    } while (0)

// One step at sliding offset k (compile-time): lazy pred of step sp=s+k-1,
// cells read xw[k..k+15], incoming pred -> xw[15+k].
#define SUBSTEP(k)                                                            \
    do {                                                                      \
        const float pm = pend * wlk;   /* pend final since prev sub-step */   \
        CELL(xw[(k)]);                                                        \
        const float p = row_sum_nohead(pm) + bl;                              \
        xw[15 + (k)] = fmaf(p, wij, bj);                                      \
        const int sp = s + (k) - 1;                                           \
        if (sp == j)      pout0 = p;                                          \
        if (sp == j + 64) pout1 = p;                                          \
        _Pragma("unroll")                                                     \
        for (int t = 1; t < A_; ++t) CELL(xw[(k) + t]);                       \
        pend = hk;                                                            \
    } while (0)

__global__ __launch_bounds__(64) void lstm_decoder_kernel(
    const float* __restrict__ y,     // (B,16)
    const float* __restrict__ u,     // (B,128)
    const float* __restrict__ W_ih,  // (64,1)
    const float* __restrict__ W_hh,  // (64,16)
    const float* __restrict__ b_ih,  // (64)
    const float* __restrict__ b_hh,  // (64)
    const float* __restrict__ W_lin, // (1,16)
    const float* __restrict__ b_lin, // (1)
    const float* __restrict__ W_h0,  // (16,128)
    const float* __restrict__ b_h0,  // (16)
    const float* __restrict__ W_c0,  // (16,128)
    const float* __restrict__ b_c0,  // (16)
    float* __restrict__ out)         // (B,144)
{
    const int b  = blockIdx.x;    // batch chain
    const int j  = threadIdx.x;   // lane 0..63
    const int kp = j & 15;        // hidden index this lane carries

    __shared__ float lds_u[R_];
    __shared__ float lds_h[H_];
    __shared__ float lds_c[H_];

    // ---- stage u[b,:] to LDS (coalesced) ----
    lds_u[j]      = u[b * R_ + j];
    lds_u[j + 64] = u[b * R_ + j + 64];
    __syncthreads();

    // ---- h0 / c0 init: lanes 0..15 -> h0[kp], lanes 16..31 -> c0[kp] ----
    if (j < 32) {
        const float* Wr = (j < 16) ? (W_h0 + kp * R_) : (W_c0 + kp * R_);
        float acc = (j < 16) ? b_h0[kp] : b_c0[kp];
        #pragma unroll
        for (int r = 0; r < R_; r += 4) {
            float4 wv = *(const float4*)(Wr + r);
            float4 uv = *(const float4*)(&lds_u[r]);
            acc = fmaf(wv.x, uv.x, acc);
            acc = fmaf(wv.y, uv.y, acc);
            acc = fmaf(wv.z, uv.z, acc);
            acc = fmaf(wv.w, uv.w, acc);
        }
        if (j < 16) lds_h[kp] = acc;
        else        lds_c[kp] = acc;
    }

    // ---- probe 1: DPP row_ror direction ----
    const int probe = __builtin_amdgcn_update_dpp(0, kp, 0x121, 0xF, 0xF, true);
    const bool plus = (probe == ((kp + 1) & 15));

    // ---- probe 2: gate-exchange slot->row mapping; relabel this lane ----
    const float rowf = (float)(j >> 4);
    float pr0, pr1, pr2, pr3;
    gate_xchg(rowf, kp, pr0, pr1, pr2, pr3);
    const int m = (pr0 == rowf) ? 0 : (pr1 == rowf) ? 1 : (pr2 == rowf) ? 2 : 3;

    // ---- per-lane pre-scaled, pre-permuted weights for gate m of kp ----
    const float LOG2E = 1.4426950408889634f;
    const float cK    = -2.0f * LOG2E;           // tanh(c) exp2 scale
    const bool  isg   = (m == 2);
    const float sj    = isg ? (-2.0f * LOG2E) : (-LOG2E);
    const int   grow  = 16 * m + kp;             // row of W_hh for my gate
    float w16[H_];
    #pragma unroll
    for (int r = 0; r < H_; ++r) {
        const int idx = plus ? ((kp + r) & 15) : ((kp - r) & 15);
        w16[r] = sj * W_hh[grow * H_ + idx];
    }
    const float bj  = sj * (b_ih[grow] + b_hh[grow]);
    const float wij = sj * W_ih[grow];
    const float aAct = isg ? 2.0f : ((m == 0) ? cK : 1.0f);
    const float bAct = isg ? -1.0f : 0.0f;
    const float wlk  = W_lin[kp];                // own-lane W_lin element
    const float bl   = b_lin[0];

    __syncthreads();
    float hk = lds_h[kp];          // h[kp], replicated across the 4 rows
    float c  = cK * lds_c[kp];     // c in SCALED domain: c' = cK * c_nat

    // ---- sliding pre-transformed window: 19 physical slots ----
    float xw[A_ + 3];
    #pragma unroll
    for (int t = 0; t < A_; ++t) xw[t] = fmaf(y[b * A_ + t], wij, bj);

    float pout0 = 0.f, pout1 = 0.f;
    float pend;                    // h snapshot with a pending pred

    // ---- step 0 (peeled; no pending pred yet) ----
    #pragma unroll
    for (int t = 0; t < A_; ++t) CELL(xw[t]);
    #pragma unroll
    for (int t = 0; t < A_ - 1; ++t) xw[t] = xw[t + 1];
    pend = hk;

    // ---- steps 1..124: 31 iterations x 4 sub-steps, sliding window ----
    int s = 1;
    #pragma unroll 1
    for (int q = 0; q < 31; ++q) {
        SUBSTEP(0);
        SUBSTEP(1);
        SUBSTEP(2);
        SUBSTEP(3);
        // one shift-by-4 per 4 steps (logical slots 0..14 = phys 4..18)
        #pragma unroll
        for (int t = 0; t < A_ - 1; ++t) xw[t] = xw[t + 4];
        s += 4;
    }

    // ---- steps 125..127: classic shift-by-1 tail ----
    #pragma unroll 1
    for (int q = 0; q < 3; ++q) {
        const float pm = pend * wlk;
        CELL(xw[0]);
        const float p = row_sum_nohead(pm) + bl;
        xw[A_ - 1] = fmaf(p, wij, bj);
        const int sp = s - 1;
        if (sp == j)      pout0 = p;
        if (sp == j + 64) pout1 = p;
        #pragma unroll
        for (int t = 1; t < A_; ++t) CELL(xw[t]);
        #pragma unroll
        for (int t = 0; t < A_ - 1; ++t) xw[t] = xw[t + 1];
        pend = hk;
        ++s;
    }

    // ---- final pred (step 127) ----
    {
        const float p = row_sum(pend * wlk) + bl;
        if (T_ - 1 == j + 64) pout1 = p;   // lane 63
    }

    // ---- output: out[b,0:16]=y[b,:], out[b,16+s]=pred_s ----
    if (j < A_) out[b * (A_ + T_) + j] = y[b * A_ + j];
    out[b * (A_ + T_) + A_ + j]      = pout0;
    out[b * (A_ + T_) + A_ + 64 + j] = pout1;
}

extern "C" void kernel_launch(void* const* d_in, const int* in_sizes, int n_in,
                              void* d_out, int out_size, void* d_ws, size_t ws_size,
                              hipStream_t stream) {
    const float* y     = (const float*)d_in[0];
    const float* u     = (const float*)d_in[1];
    const float* W_ih  = (const float*)d_in[2];
    const float* W_hh  = (const float*)d_in[3];
    const float* b_ih  = (const float*)d_in[4];
    const float* b_hh  = (const float*)d_in[5];
    const float* W_lin = (const float*)d_in[6];
    const float* b_lin = (const float*)d_in[7];
    const float* W_h0  = (const float*)d_in[8];
    const float* b_h0  = (const float*)d_in[9];
    const float* W_c0  = (const float*)d_in[10];
    const float* b_c0  = (const float*)d_in[11];
    float* out = (float*)d_out;

    lstm_decoder_kernel<<<B_, 64, 0, stream>>>(
        y, u, W_ih, W_hh, b_ih, b_hh, W_lin, b_lin,
        W_h0, b_h0, W_c0, b_c0, out);
}

// Round 5
// 261.898 us; speedup vs baseline: 1.0131x; 1.0131x over previous
//
#include <hip/hip_runtime.h>

// LSTM decoder: B=1024, H=16, 4H=64 gates, T=128 steps x 16 cells = 2048
// strictly-serial cell evaluations per batch chain. 1 chain = 1 wave =
// 1 SIMD (occupancy structurally pinned; all hiding is intra-wave ILP).
//
// Round-20 = REVERT to round-18 (203.1us, absmax 0.0) structure.
// Round-19's two changes are backed out with evidence:
//  - row_sum_nohead CORRUPTED NUMERICS (absmax 0.0317): the compiler sank
//    pm=pend*wlk to just before the asm, violating the VALU-write ->
//    DPP-read 2-wait-state hazard. Hazard guards must live IN the asm.
//  - x4 step unroll was NET-NEGATIVE (+4.5us): FETCH_SIZE 559->683 KB
//    shows the 4x loop body paying I$ miss traffic > the ~1.4 cyc/cell
//    saved on shift movs. This kernel is compact-code-sensitive.
// Kept from round-19: pm hoisted above CELL(xw[0]) (harmless scheduling
// hint), with row_sum's head s_nop RETAINED for hazard safety.
//
// Experiment ledger (all measured on MI355X):
//  fast_rcp for v_rcp: +23% (latency-bound, not trans-bound) - reverted.
//  pre-transformed window: -5.3us - kept.
//  lazy pred + nop cut: -4.3us - kept.
//  x4 unroll / 19-slot window: +4.5us + numerics - reverted.
//
// Carried: per-lane one-gate mapping relabeled by probed permlane slots;
// 15 v_mul/v_fmac_f32_dpp fused gather-MACs (asm); 3 permlane16/32_swap
// gate exchange; c in exp2-scaled domain; tanh tail fmaf(-ov,ec,ov)*rcp;
// DPP row-sum pred; lazy pred; pre-transformed window; s-loop unroll x2.

#define B_ 1024
#define A_ 16
#define T_ 128
#define R_ 128
#define H_ 16

typedef unsigned int u32x2 __attribute__((ext_vector_type(2)));

// Broadcast the 4 gate rows to all lanes (slot order probed at init).
__device__ __forceinline__ void gate_xchg(float act, int kp,
                                          float& s0, float& s1,
                                          float& s2, float& s3) {
#if __has_builtin(__builtin_amdgcn_permlane32_swap) && __has_builtin(__builtin_amdgcn_permlane16_swap)
    const unsigned a = __float_as_uint(act);
    const u32x2 pq = __builtin_amdgcn_permlane32_swap(a, a, false, false);
    const u32x2 rs = __builtin_amdgcn_permlane16_swap(pq.x, pq.x, false, false);
    const u32x2 tu = __builtin_amdgcn_permlane16_swap(pq.y, pq.y, false, false);
    s0 = __uint_as_float(rs.x); s1 = __uint_as_float(rs.y);
    s2 = __uint_as_float(tu.x); s3 = __uint_as_float(tu.y);
#else
    s0 = __shfl(act, kp,      64);
    s1 = __shfl(act, kp + 16, 64);
    s2 = __shfl(act, kp + 32, 64);
    s3 = __shfl(act, kp + 48, 64);
#endif
}

// Row-wide sum via DPP rotations: every lane ends with sum over its 16-lane
// row. Direction-agnostic (any consistent rotation gives a complete tree).
// Head s_nop is MANDATORY: the input mul may be scheduled immediately
// before this asm (VALU-write -> DPP-read needs 2 wait states; violating
// it corrupts data -- measured in round-19, absmax 0.0317).
__device__ __forceinline__ float row_sum(float m) {
    float pm = m;
    asm("s_nop 1\n\t"
        "v_add_f32_dpp %0, %0, %0 row_ror:8 row_mask:0xf bank_mask:0xf\n\t"
        "s_nop 1\n\t"
        "v_add_f32_dpp %0, %0, %0 row_ror:4 row_mask:0xf bank_mask:0xf\n\t"
        "s_nop 1\n\t"
        "v_add_f32_dpp %0, %0, %0 row_ror:2 row_mask:0xf bank_mask:0xf\n\t"
        "s_nop 1\n\t"
        "v_add_f32_dpp %0, %0, %0 row_ror:1 row_mask:0xf bank_mask:0xf"
        : "+v"(pm));
    return pm;
}

// One LSTM cell; xz = fmaf(x, wij, bj) precomputed (pre-transformed window).
// Hazard note: fmaf(hk, w16[0], z0) reads hk and writes asm input z0, so it
// cannot be scheduled out from between hk's def and the asm block -> >=2
// cycles between the v_mul that writes hk and the first DPP read of hk.
#define CELL(xz)                                                              \
    do {                                                                      \
        float z0 = fmaf(hk, w16[0], (xz));                                    \
        float z1, z2, z3;                                                     \
        asm("v_mul_f32_dpp  %1, %4, %6  row_ror:1  row_mask:0xf bank_mask:0xf\n\t" \
            "v_mul_f32_dpp  %2, %4, %7  row_ror:2  row_mask:0xf bank_mask:0xf\n\t" \
            "v_mul_f32_dpp  %3, %4, %8  row_ror:3  row_mask:0xf bank_mask:0xf\n\t" \
            "v_fmac_f32_dpp %0, %4, %9  row_ror:4  row_mask:0xf bank_mask:0xf\n\t" \
            "v_fmac_f32_dpp %1, %4, %10 row_ror:5  row_mask:0xf bank_mask:0xf\n\t" \
            "v_fmac_f32_dpp %2, %4, %11 row_ror:6  row_mask:0xf bank_mask:0xf\n\t" \
            "v_fmac_f32_dpp %3, %4, %12 row_ror:7  row_mask:0xf bank_mask:0xf\n\t" \
            "v_fmac_f32_dpp %0, %4, %13 row_ror:8  row_mask:0xf bank_mask:0xf\n\t" \
            "v_fmac_f32_dpp %1, %4, %14 row_ror:9  row_mask:0xf bank_mask:0xf\n\t" \
            "v_fmac_f32_dpp %2, %4, %15 row_ror:10 row_mask:0xf bank_mask:0xf\n\t" \
            "v_fmac_f32_dpp %3, %4, %16 row_ror:11 row_mask:0xf bank_mask:0xf\n\t" \
            "v_fmac_f32_dpp %0, %4, %17 row_ror:12 row_mask:0xf bank_mask:0xf\n\t" \
            "v_fmac_f32_dpp %1, %4, %18 row_ror:13 row_mask:0xf bank_mask:0xf\n\t" \
            "v_fmac_f32_dpp %2, %4, %19 row_ror:14 row_mask:0xf bank_mask:0xf\n\t" \
            "v_fmac_f32_dpp %3, %4, %20 row_ror:15 row_mask:0xf bank_mask:0xf"     \
            : "+v"(z0), "=&v"(z1), "=&v"(z2), "=&v"(z3)                       \
            : "v"(hk),                                                        \
              "v"(w16[0]),  "v"(w16[1]),  "v"(w16[2]),  "v"(w16[3]),          \
              "v"(w16[4]),  "v"(w16[5]),  "v"(w16[6]),  "v"(w16[7]),          \
              "v"(w16[8]),  "v"(w16[9]),  "v"(w16[10]), "v"(w16[11]),         \
              "v"(w16[12]), "v"(w16[13]), "v"(w16[14]), "v"(w16[15]));        \
        const float z = (z0 + z1) + (z2 + z3);                                \
        const float e   = __builtin_amdgcn_exp2f(z);                          \
        const float sg  = __builtin_amdgcn_rcpf(1.0f + e);                    \
        const float act = fmaf(aAct, sg, bAct);                               \
        float iv, fv, gg, ov;                                                 \
        gate_xchg(act, kp, iv, fv, gg, ov);                                   \
        c = fmaf(fv, c, iv * gg);                                             \
        const float ec = __builtin_amdgcn_exp2f(c);                           \
        const float rc = __builtin_amdgcn_rcpf(1.0f + ec);                    \
        const float nm = fmaf(-ov, ec, ov);                                   \
        hk = nm * rc;                                                         \
    } while (0)

__global__ __launch_bounds__(64) void lstm_decoder_kernel(
    const float* __restrict__ y,     // (B,16)
    const float* __restrict__ u,     // (B,128)
    const float* __restrict__ W_ih,  // (64,1)
    const float* __restrict__ W_hh,  // (64,16)
    const float* __restrict__ b_ih,  // (64)
    const float* __restrict__ b_hh,  // (64)
    const float* __restrict__ W_lin, // (1,16)
    const float* __restrict__ b_lin, // (1)
    const float* __restrict__ W_h0,  // (16,128)
    const float* __restrict__ b_h0,  // (16)
    const float* __restrict__ W_c0,  // (16,128)
    const float* __restrict__ b_c0,  // (16)
    float* __restrict__ out)         // (B,144)
{
    const int b  = blockIdx.x;    // batch chain
    const int j  = threadIdx.x;   // lane 0..63
    const int kp = j & 15;        // hidden index this lane carries

    __shared__ float lds_u[R_];
    __shared__ float lds_h[H_];
    __shared__ float lds_c[H_];

    // ---- stage u[b,:] to LDS (coalesced) ----
    lds_u[j]      = u[b * R_ + j];
    lds_u[j + 64] = u[b * R_ + j + 64];
    __syncthreads();

    // ---- h0 / c0 init: lanes 0..15 -> h0[kp], lanes 16..31 -> c0[kp] ----
    if (j < 32) {
        const float* Wr = (j < 16) ? (W_h0 + kp * R_) : (W_c0 + kp * R_);
        float acc = (j < 16) ? b_h0[kp] : b_c0[kp];
        #pragma unroll
        for (int r = 0; r < R_; r += 4) {
            float4 wv = *(const float4*)(Wr + r);
            float4 uv = *(const float4*)(&lds_u[r]);
            acc = fmaf(wv.x, uv.x, acc);
            acc = fmaf(wv.y, uv.y, acc);
            acc = fmaf(wv.z, uv.z, acc);
            acc = fmaf(wv.w, uv.w, acc);
        }
        if (j < 16) lds_h[kp] = acc;
        else        lds_c[kp] = acc;
    }

    // ---- probe 1: DPP row_ror direction ----
    const int probe = __builtin_amdgcn_update_dpp(0, kp, 0x121, 0xF, 0xF, true);
    const bool plus = (probe == ((kp + 1) & 15));

    // ---- probe 2: gate-exchange slot->row mapping; relabel this lane ----
    const float rowf = (float)(j >> 4);
    float pr0, pr1, pr2, pr3;
    gate_xchg(rowf, kp, pr0, pr1, pr2, pr3);
    const int m = (pr0 == rowf) ? 0 : (pr1 == rowf) ? 1 : (pr2 == rowf) ? 2 : 3;

    // ---- per-lane pre-scaled, pre-permuted weights for gate m of kp ----
    const float LOG2E = 1.4426950408889634f;
    const float cK    = -2.0f * LOG2E;           // tanh(c) exp2 scale
    const bool  isg   = (m == 2);
    const float sj    = isg ? (-2.0f * LOG2E) : (-LOG2E);
    const int   grow  = 16 * m + kp;             // row of W_hh for my gate
    float w16[H_];
    #pragma unroll
    for (int r = 0; r < H_; ++r) {
        const int idx = plus ? ((kp + r) & 15) : ((kp - r) & 15);
        w16[r] = sj * W_hh[grow * H_ + idx];
    }
    const float bj  = sj * (b_ih[grow] + b_hh[grow]);
    const float wij = sj * W_ih[grow];
    const float aAct = isg ? 2.0f : ((m == 0) ? cK : 1.0f);
    const float bAct = isg ? -1.0f : 0.0f;
    const float wlk  = W_lin[kp];                // own-lane W_lin element
    const float bl   = b_lin[0];

    __syncthreads();
    float hk = lds_h[kp];          // h[kp], replicated across the 4 rows
    float c  = cK * lds_c[kp];     // c in SCALED domain: c' = cK * c_nat

    // ---- window kept in PRE-TRANSFORMED domain: xw[t] = fmaf(win,wij,bj)
    float xw[A_];
    #pragma unroll
    for (int t = 0; t < A_; ++t) xw[t] = fmaf(y[b * A_ + t], wij, bj);

    float pout0 = 0.f, pout1 = 0.f;
    float pend;                    // h snapshot with a pending pred

    // ---- step 0 (peeled; no pending pred yet) ----
    #pragma unroll
    for (int t = 0; t < A_; ++t) CELL(xw[t]);
    #pragma unroll
    for (int t = 0; t < A_ - 1; ++t) xw[t] = xw[t + 1];
    pend = hk;

    // ---- steps 1..127: pred of step s-1 finished lazily inside step s ----
    #pragma unroll 2
    for (int s = 1; s < T_; ++s) {
        const float pm = pend * wlk;   // hoisted; row_sum keeps head s_nop
        CELL(xw[0]);

        // pred of step s-1: row_sum chain hides under cell 0's shadows;
        // its transformed value is only needed at cell t=15.
        const float p = row_sum(pm) + bl;
        xw[A_ - 1] = fmaf(p, wij, bj);          // the ONE new fma per step
        if (s - 1 == j)      pout0 = p;
        if (s - 1 == j + 64) pout1 = p;

        #pragma unroll
        for (int t = 1; t < A_; ++t) CELL(xw[t]);

        #pragma unroll
        for (int t = 0; t < A_ - 1; ++t) xw[t] = xw[t + 1];
        pend = hk;
    }

    // ---- final pred (step 127) ----
    {
        const float p = row_sum(pend * wlk) + bl;
        if (T_ - 1 == j + 64) pout1 = p;   // lane 63
    }

    // ---- output: out[b,0:16]=y[b,:], out[b,16+s]=pred_s ----
    if (j < A_) out[b * (A_ + T_) + j] = y[b * A_ + j];
    out[b * (A_ + T_) + A_ + j]      = pout0;
    out[b * (A_ + T_) + A_ + 64 + j] = pout1;
}

extern "C" void kernel_launch(void* const* d_in, const int* in_sizes, int n_in,
                              void* d_out, int out_size, void* d_ws, size_t ws_size,
                              hipStream_t stream) {
    const float* y     = (const float*)d_in[0];
    const float* u     = (const float*)d_in[1];
    const float* W_ih  = (const float*)d_in[2];
    const float* W_hh  = (const float*)d_in[3];
    const float* b_ih  = (const float*)d_in[4];
    const float* b_hh  = (const float*)d_in[5];
    const float* W_lin = (const float*)d_in[6];
    const float* b_lin = (const float*)d_in[7];
    const float* W_h0  = (const float*)d_in[8];
    const float* b_h0  = (const float*)d_in[9];
    const float* W_c0  = (const float*)d_in[10];
    const float* b_c0  = (const float*)d_in[11];
    float* out = (float*)d_out;

    lstm_decoder_kernel<<<B_, 64, 0, stream>>>(
        y, u, W_ih, W_hh, b_ih, b_hh, W_lin, b_lin,
        W_h0, b_h0, W_c0, b_c0, out);
}